// Round 12
// baseline (901.653 us; speedup 1.0000x reference)
//
#include <hip/hip_runtime.h>

#define DI static __device__ __forceinline__

typedef __attribute__((ext_vector_type(8))) short bf16x8;
typedef __attribute__((ext_vector_type(4))) float f32x4;

DI unsigned short f2bf(float f) {
  unsigned int u = __float_as_uint(f);
  u = (u + 0x7fffu + ((u >> 16) & 1u)) >> 16;
  return (unsigned short)u;
}
DI float bf2f(unsigned short h) { return __uint_as_float(((unsigned int)h) << 16); }

// DPP wave64 reduce steps (VALU pipe).
#define DPP_MAXU(v, ctrl)                                                      \
  {                                                                            \
    unsigned o_ = (unsigned)__builtin_amdgcn_update_dpp((int)(v), (int)(v),    \
                                                        (ctrl), 0xf, 0xf, false); \
    (v) = (o_ > (v)) ? o_ : (v);                                               \
  }
#define DPP_MINU(v, ctrl)                                                      \
  {                                                                            \
    unsigned o_ = (unsigned)__builtin_amdgcn_update_dpp((int)(v), (int)(v),    \
                                                        (ctrl), 0xf, 0xf, false); \
    (v) = (o_ < (v)) ? o_ : (v);                                               \
  }

// ---------------------------------------------------------------------------
// FPS: one block per batch, 256 threads (4 waves), 16 points/thread.
// r12: distance loop back to scalar float[16] arrays (r3-verified exact rn
// sequence, index = t + j*256, ascending j, strict >). v2f was being
// scalarized by the compiler WITH pack/unpack overhead — scalar arrays give
// the same bits with fewer moves. Reduce path (DPP + 1 barrier + slots)
// unchanged from r7-r11 (verified 5 rounds). slot alignas(32) so the 32B
// post-barrier key read merges to b128s.
// ---------------------------------------------------------------------------
__global__ __launch_bounds__(256) void fps_kernel(const float* __restrict__ xyz,
                                                  float* __restrict__ newxyz) {
  const int b = blockIdx.x;
  const int t = threadIdx.x;
  const int lane = t & 63, wid = t >> 6;  // 4 waves
  const float* X = xyz + (size_t)b * 4096 * 3;
  __shared__ float XL[4096 * 3];
  __shared__ int FI[1024];
  __shared__ alignas(32) unsigned long long slot[2][4];
  for (int idx = t; idx < 12288; idx += 256) XL[idx] = X[idx];
  float px[16], py[16], pz[16], dist[16];
#pragma unroll
  for (int j = 0; j < 16; ++j) {
    int i = t + (j << 8);
    px[j] = X[i * 3 + 0];
    py[j] = X[i * 3 + 1];
    pz[j] = X[i * 3 + 2];
    dist[j] = 3.402823466e38f;
  }
  __syncthreads();
  float cx = XL[0], cy = XL[1], cz = XL[2];  // farthest = 0 initially
  int fi = 0;
  for (int s = 0; s < 1024; ++s) {
    if (t == 0) FI[s] = fi;
    float bv = -1.0f;
    unsigned int bi = 0;
#pragma unroll
    for (int j = 0; j < 16; ++j) {
      float dx = __fsub_rn(px[j], cx);
      float dy = __fsub_rn(py[j], cy);
      float dz = __fsub_rn(pz[j], cz);
      float d = __fadd_rn(__fadd_rn(__fmul_rn(dx, dx), __fmul_rn(dy, dy)), __fmul_rn(dz, dz));
      float nd = fminf(dist[j], d);
      dist[j] = nd;
      bool better = (nd > bv);  // strict >: earlier (smaller) index kept on ties
      bv = better ? nd : bv;
      bi = better ? (unsigned)(t + (j << 8)) : bi;
    }
    // ---- phase 1: wave max of dist bits (DPP, VALU-latency) ----
    unsigned vb = __float_as_uint(bv);  // bv >= 0 -> uint order == float order
    unsigned m = vb;
    DPP_MAXU(m, 0x111);  // row_shr:1
    DPP_MAXU(m, 0x112);  // row_shr:2
    DPP_MAXU(m, 0x114);  // row_shr:4
    DPP_MAXU(m, 0x118);  // row_shr:8
    DPP_MAXU(m, 0x142);  // row_bcast:15
    DPP_MAXU(m, 0x143);  // row_bcast:31
    unsigned wmax = (unsigned)__builtin_amdgcn_readlane((int)m, 63);
    // ---- phase 2: wave min index among lanes at the max ----
    unsigned ik = (vb == wmax) ? bi : 0xFFFFFFFFu;
    DPP_MINU(ik, 0x111);
    DPP_MINU(ik, 0x112);
    DPP_MINU(ik, 0x114);
    DPP_MINU(ik, 0x118);
    DPP_MINU(ik, 0x142);
    DPP_MINU(ik, 0x143);
    unsigned widx = (unsigned)__builtin_amdgcn_readlane((int)ik, 63);
    const int p = s & 1;
    if (lane == 0)
      slot[p][wid] = ((unsigned long long)wmax << 32) | (unsigned long long)(~widx);
    __syncthreads();
    // 4-way block winner: max key == max dist, tie -> min idx (bigger ~idx)
    unsigned long long k0 = slot[p][0], k1 = slot[p][1];
    unsigned long long k2 = slot[p][2], k3 = slot[p][3];
    unsigned long long m01 = (k0 >= k1) ? k0 : k1;
    unsigned long long m23 = (k2 >= k3) ? k2 : k3;
    unsigned long long win = (m01 >= m23) ? m01 : m23;
    fi = (int)(~(unsigned int)win);  // winner index in [0,4095]
    cx = XL[fi * 3 + 0];
    cy = XL[fi * 3 + 1];
    cz = XL[fi * 3 + 2];
  }
  __syncthreads();
  // batched centroid write-out (once per kernel)
  float* out = newxyz + (size_t)b * 1024 * 3;
  for (int s2 = t; s2 < 1024; s2 += 256) {
    int f = FI[s2];
    out[s2 * 3 + 0] = XL[f * 3 + 0];
    out[s2 * 3 + 1] = XL[f * 3 + 1];
    out[s2 * 3 + 2] = XL[f * 3 + 2];
  }
}

// ---------------------------------------------------------------------------
// P0[b][n][o] = sum_c W0[o][3+c] * points[b][c][n]
// r12: W staged to registers per 16-c chunk (removes 2 LDS b128/iter from
// the inner loop). Same fmaf order per acc element -> bit-identical P0.
// ---------------------------------------------------------------------------
__global__ __launch_bounds__(256) void p0_kernel(const float* __restrict__ points,
                                                 const float* __restrict__ w0,
                                                 float* __restrict__ P0) {
  const int b = blockIdx.x >> 6;
  const int n0 = (blockIdx.x & 63) << 6;
  const int t = threadIdx.x;
  __shared__ float W[64][64];  // [c][o]
  for (int idx = t; idx < 4096; idx += 256) {
    int c = idx >> 6, o = idx & 63;
    W[c][o] = w0[o * 67 + 3 + c];
  }
  __syncthreads();
  const int i = t >> 4, j = t & 15;
  const float* Pb = points + (size_t)b * 64 * 4096 + n0 + 4 * i;
  float acc[4][4] = {};
  for (int ch = 0; ch < 4; ++ch) {
    float wr[16][4];
#pragma unroll
    for (int cc = 0; cc < 16; ++cc) {
      float4 wv = *(const float4*)&W[ch * 16 + cc][4 * j];
      wr[cc][0] = wv.x; wr[cc][1] = wv.y; wr[cc][2] = wv.z; wr[cc][3] = wv.w;
    }
#pragma unroll
    for (int cc = 0; cc < 16; ++cc) {
      int c = ch * 16 + cc;
      float4 xv = *(const float4*)(Pb + (size_t)c * 4096);
      float xr[4] = {xv.x, xv.y, xv.z, xv.w};
#pragma unroll
      for (int rr = 0; rr < 4; ++rr)
#pragma unroll
        for (int oi = 0; oi < 4; ++oi) acc[rr][oi] = fmaf(xr[rr], wr[cc][oi], acc[rr][oi]);
    }
  }
#pragma unroll
  for (int rr = 0; rr < 4; ++rr) {
    float4 vv = make_float4(acc[rr][0], acc[rr][1], acc[rr][2], acc[rr][3]);
    *(float4*)(P0 + ((size_t)b * 4096 + n0 + 4 * i + rr) * 64 + 4 * j) = vv;
  }
}

// ---------------------------------------------------------------------------
// Ball query fused with layer-0 stats (XLA-CPU fp32 emulation VERIFIED r3).
// ---------------------------------------------------------------------------
__global__ __launch_bounds__(256) void ballquery_stats0_kernel(
    const float* __restrict__ xyz, const float* __restrict__ newxyz,
    const float* __restrict__ P0, const float* __restrict__ w0,
    int* __restrict__ gidx, float* __restrict__ partials0) {
  const int t = threadIdx.x;
  const int lane = t & 63, w = t >> 6;
  const int gid = blockIdx.x * 4 + w;  // 0..16383
  const int b = gid >> 10;
  __shared__ int sel[4][32];
  __shared__ float red[4][128];
  const float* Xb = xyz + (size_t)b * 4096 * 3;
  const float cx = newxyz[(size_t)gid * 3 + 0];
  const float cy = newxyz[(size_t)gid * 3 + 1];
  const float cz = newxyz[(size_t)gid * 3 + 2];
  const float cs = __fadd_rn(__fadd_rn(__fmul_rn(cx, cx), __fmul_rn(cy, cy)), __fmul_rn(cz, cz));
  int cnt = 0, first = 0;
  bool found = false;
  for (int base = 0; base < 4096; base += 64) {
    int i = base + lane;
    float x = Xb[i * 3 + 0], y = Xb[i * 3 + 1], z = Xb[i * 3 + 2];
    float xs = __fadd_rn(__fadd_rn(__fmul_rn(x, x), __fmul_rn(y, y)), __fmul_rn(z, z));
    float dot = fmaf(cz, z, fmaf(cy, y, __fmul_rn(cx, x)));  // fma chain, d=0,1,2
    float sqr = __fsub_rn(__fadd_rn(cs, xs), __fmul_rn(2.0f, dot));
    bool ok = sqr <= 0.04f;
    unsigned long long mask = __ballot(ok);
    if (!found && mask != 0ull) { first = base + __builtin_ctzll(mask); found = true; }
    int pre = __popcll(mask & ((1ull << lane) - 1ull));
    int pos = cnt + pre;
    if (ok && pos < 32) sel[w][pos] = i;
    cnt += (int)__popcll(mask);
    if (cnt >= 32) break;
  }
  if (cnt < 32) {
    int pad = found ? first : 0;
    for (int p = cnt + lane; p < 32; p += 64) sel[w][p] = pad;
  }
  __syncthreads();
  if (lane < 32) gidx[(size_t)gid * 32 + lane] = sel[w][lane];
  const int c = lane;
  float wx = w0[c * 67 + 0], wy = w0[c * 67 + 1], wz = w0[c * 67 + 2];
  float ssum = 0.f, ssq = 0.f;
  const float* P0b = P0 + (size_t)b * 4096 * 64;
  for (int k = 0; k < 32; ++k) {
    int g = sel[w][k];
    float gx = Xb[g * 3 + 0] - cx, gy = Xb[g * 3 + 1] - cy, gz = Xb[g * 3 + 2] - cz;
    float a0 = fmaf(wx, gx, fmaf(wy, gy, fmaf(wz, gz, P0b[(size_t)g * 64 + c])));
    ssum += a0;
    ssq = fmaf(a0, a0, ssq);
  }
  red[w][c] = ssum;
  red[w][c + 64] = ssq;
  __syncthreads();
  if (t < 128) {
    float acc = red[0][t] + red[1][t] + red[2][t] + red[3][t];
    partials0[(size_t)t * 4096 + blockIdx.x] = acc;
  }
}

// ---------------------------------------------------------------------------
// finalize BN stats: scale = g*rsqrt(var+eps), shift = b - mean*scale
// ---------------------------------------------------------------------------
__global__ __launch_bounds__(256) void finalize_kernel(
    const float* __restrict__ partials, int C, int nblk,
    const float* __restrict__ gamma, const float* __restrict__ beta,
    float* __restrict__ scale, float* __restrict__ shift) {
  const int c = blockIdx.x, t = threadIdx.x;
  double s1 = 0.0, s2 = 0.0;
  for (int k = t; k < nblk; k += 256) {
    s1 += (double)partials[(size_t)c * nblk + k];
    s2 += (double)partials[(size_t)(C + c) * nblk + k];
  }
  __shared__ double r1[256], r2[256];
  r1[t] = s1;
  r2[t] = s2;
  __syncthreads();
  for (int off = 128; off > 0; off >>= 1) {
    if (t < off) { r1[t] += r1[t + off]; r2[t] += r2[t + off]; }
    __syncthreads();
  }
  if (t == 0) {
    const double M = 524288.0;
    double mean = r1[0] / M;
    double var = r2[0] / M - mean * mean;
    if (var < 0.0) var = 0.0;
    float sc = gamma[c] * (float)(1.0 / sqrt(var + 1e-5));
    scale[c] = sc;
    shift[c] = beta[c] - (float)mean * sc;
  }
}

// ---------------------------------------------------------------------------
// P2 (MFMA): act1_raw = W1 * relu(bn0(act0)); LDS C-staging for coalesced
// act1 stores (VERIFIED r11).
// ---------------------------------------------------------------------------
__global__ __launch_bounds__(256) void p2_kernel(
    const float* __restrict__ xyz, const float* __restrict__ newxyz,
    const float* __restrict__ P0, const int* __restrict__ gidx,
    const float* __restrict__ w0, const float* __restrict__ w1,
    const float* __restrict__ sc0g, const float* __restrict__ sh0g,
    unsigned short* __restrict__ act1, float* __restrict__ partials1) {
  __shared__ unsigned short W1T[64 * 72];  // [o][c] bf16, pad 72
  __shared__ unsigned short A[64 * 72];    // [r][c] bf16, pad 72
  __shared__ unsigned short Cs[64 * 72];   // [r][o] bf16 staging, pad 72
  __shared__ float S1r[4][68], S2r[4][68];
  __shared__ float w0x[64], w0y[64], w0z[64], sc0[64], sh0[64];
  const int t = threadIdx.x;
  const int lane = t & 63, w = t >> 6;
  const int quad = lane >> 4, l15 = lane & 15;
  for (int idx = t; idx < 4096; idx += 256) {
    int o = idx >> 6, c = idx & 63;
    W1T[o * 72 + c] = f2bf(w1[o * 64 + c]);
  }
  if (t < 64) {
    w0x[t] = w0[t * 67 + 0];
    w0y[t] = w0[t * 67 + 1];
    w0z[t] = w0[t * 67 + 2];
    sc0[t] = sc0g[t];
    sh0[t] = sh0g[t];
  }
  __syncthreads();
  const int rl = t >> 2, cq = t & 3;
  float ssum[4] = {}, ssq[4] = {};
  for (int tile = 0; tile < 8; ++tile) {
    const int rowbase = (blockIdx.x * 8 + tile) << 6;
    {
      int r = rowbase + rl;
      int b = r >> 15, s = (r >> 5) & 1023;
      int g = gidx[r];
      const float* Pt = xyz + ((size_t)b * 4096 + g) * 3;
      const float* Ct = newxyz + ((size_t)b * 1024 + s) * 3;
      float dx = Pt[0] - Ct[0], dy = Pt[1] - Ct[1], dz = Pt[2] - Ct[2];
      const float4* p4 = (const float4*)(P0 + ((size_t)b * 4096 + g) * 64 + cq * 16);
      float4 a0 = p4[0], a1 = p4[1], a2 = p4[2], a3 = p4[3];
      float pv[16] = {a0.x, a0.y, a0.z, a0.w, a1.x, a1.y, a1.z, a1.w,
                      a2.x, a2.y, a2.z, a2.w, a3.x, a3.y, a3.z, a3.w};
      unsigned pk[8];
#pragma unroll
      for (int q = 0; q < 8; ++q) {
        int c0 = cq * 16 + 2 * q, c1 = c0 + 1;
        float aa = fmaf(w0x[c0], dx, fmaf(w0y[c0], dy, fmaf(w0z[c0], dz, pv[2 * q])));
        float bb = fmaf(w0x[c1], dx, fmaf(w0y[c1], dy, fmaf(w0z[c1], dz, pv[2 * q + 1])));
        float r0 = fmaxf(0.f, fmaf(aa, sc0[c0], sh0[c0]));
        float r1 = fmaxf(0.f, fmaf(bb, sc0[c1], sh0[c1]));
        pk[q] = (unsigned)f2bf(r0) | ((unsigned)f2bf(r1) << 16);
      }
      uint4* dst = (uint4*)&A[rl * 72 + cq * 16];
      dst[0] = make_uint4(pk[0], pk[1], pk[2], pk[3]);
      dst[1] = make_uint4(pk[4], pk[5], pk[6], pk[7]);
    }
    __syncthreads();  // S1: A visible
    const unsigned short* Arow = &A[(w * 16 + l15) * 72 + quad * 8];
    bf16x8 a0 = *(const bf16x8*)(Arow);
    bf16x8 a1 = *(const bf16x8*)(Arow + 32);
#pragma unroll
    for (int nt = 0; nt < 4; ++nt) {
      const unsigned short* Brow = &W1T[(nt * 16 + l15) * 72 + quad * 8];
      bf16x8 b0 = *(const bf16x8*)(Brow);
      bf16x8 b1 = *(const bf16x8*)(Brow + 32);
      f32x4 c0 = {0.f, 0.f, 0.f, 0.f};
      c0 = __builtin_amdgcn_mfma_f32_16x16x32_bf16(a0, b0, c0, 0, 0, 0);
      c0 = __builtin_amdgcn_mfma_f32_16x16x32_bf16(a1, b1, c0, 0, 0, 0);
      int o = nt * 16 + l15;
      int rloc = w * 16 + quad * 4;
#pragma unroll
      for (int reg = 0; reg < 4; ++reg) {
        float y = c0[reg];
        ssum[nt] += y;
        ssq[nt] = fmaf(y, y, ssq[nt]);
        Cs[(rloc + reg) * 72 + o] = f2bf(y);
      }
    }
    __syncthreads();  // S2: Cs complete (also: all MFMA reads of A done)
    {
      const uint4* src = (const uint4*)&Cs[rl * 72 + cq * 16];
      uint4 v0 = src[0], v1 = src[1];
      uint4* dst = (uint4*)(act1 + ((size_t)rowbase + rl) * 64 + cq * 16);
      dst[0] = v0;
      dst[1] = v1;
    }
  }
#pragma unroll
  for (int nt = 0; nt < 4; ++nt) {
    float s1 = ssum[nt];
    s1 += __shfl_xor(s1, 16, 64);
    s1 += __shfl_xor(s1, 32, 64);
    float s2 = ssq[nt];
    s2 += __shfl_xor(s2, 16, 64);
    s2 += __shfl_xor(s2, 32, 64);
    if (quad == 0) {
      S1r[w][nt * 16 + l15] = s1;
      S2r[w][nt * 16 + l15] = s2;
    }
  }
  __syncthreads();
  if (t < 64) {
    int o = t;
    float s1 = S1r[0][o] + S1r[1][o] + S1r[2][o] + S1r[3][o];
    float s2 = S2r[0][o] + S2r[1][o] + S2r[2][o] + S2r[3][o];
    partials1[(size_t)o * 1024 + blockIdx.x] = s1;
    partials1[(size_t)(64 + o) * 1024 + blockIdx.x] = s2;
  }
}

// ---------------------------------------------------------------------------
// P3 (MFMA): act2_raw = W2 * relu(bn1(act1)) (VERIFIED r9/r11).
// gmx/gmn in [b][s][o] (coalesced).
// ---------------------------------------------------------------------------
__global__ __launch_bounds__(256) void p3_kernel(
    const unsigned short* __restrict__ act1, const float* __restrict__ w2,
    const float* __restrict__ sc1g, const float* __restrict__ sh1g,
    float* __restrict__ partials2, float* __restrict__ gmx,
    float* __restrict__ gmn) {
  __shared__ unsigned short W2T[128 * 72];  // [o][c] bf16, pad 72
  __shared__ unsigned short A[64 * 72];     // [r][k] bf16, pad 72
  __shared__ float Mred[4][132], Nred[4][132];
  __shared__ float S1r[4][132], S2r[4][132];
  __shared__ float sc1[64], sh1[64];
  const int t = threadIdx.x;
  const int lane = t & 63, w = t >> 6;
  const int quad = lane >> 4, l15 = lane & 15;
  for (int idx = t; idx < 8192; idx += 256) {
    int o = idx >> 6, c = idx & 63;
    W2T[o * 72 + c] = f2bf(w2[o * 64 + c]);
  }
  if (t < 64) { sc1[t] = sc1g[t]; sh1[t] = sh1g[t]; }
  __syncthreads();
  const int rl = t >> 2, cq = t & 3;
  float ssum[8] = {}, ssq[8] = {};
  for (int tile = 0; tile < 8; ++tile) {
    const int rowbase = (blockIdx.x * 8 + tile) << 6;
    {
      size_t r = (size_t)rowbase + rl;
      const uint4* pr = (const uint4*)(act1 + r * 64 + cq * 16);
      uint4 aa = pr[0], bb = pr[1];
      unsigned int uu[8] = {aa.x, aa.y, aa.z, aa.w, bb.x, bb.y, bb.z, bb.w};
      unsigned int pk[8];
#pragma unroll
      for (int q = 0; q < 8; ++q) {
        int c = cq * 16 + 2 * q;
        float v0 = bf2f((unsigned short)(uu[q] & 0xffffu));
        float v1 = bf2f((unsigned short)(uu[q] >> 16));
        float r0 = fmaxf(0.f, fmaf(v0, sc1[c], sh1[c]));
        float r1 = fmaxf(0.f, fmaf(v1, sc1[c + 1], sh1[c + 1]));
        pk[q] = (unsigned)f2bf(r0) | ((unsigned)f2bf(r1) << 16);
      }
      uint4* dst = (uint4*)&A[rl * 72 + cq * 16];
      dst[0] = make_uint4(pk[0], pk[1], pk[2], pk[3]);
      dst[1] = make_uint4(pk[4], pk[5], pk[6], pk[7]);
    }
    __syncthreads();  // S1: A visible
    const unsigned short* Arow = &A[(w * 16 + l15) * 72 + quad * 8];
    bf16x8 a0 = *(const bf16x8*)(Arow);
    bf16x8 a1 = *(const bf16x8*)(Arow + 32);
    f32x4 acc[8];
#pragma unroll
    for (int nt = 0; nt < 8; ++nt) {
      const unsigned short* Brow = &W2T[(nt * 16 + l15) * 72 + quad * 8];
      bf16x8 b0 = *(const bf16x8*)(Brow);
      bf16x8 b1 = *(const bf16x8*)(Brow + 32);
      f32x4 c0 = {0.f, 0.f, 0.f, 0.f};
      c0 = __builtin_amdgcn_mfma_f32_16x16x32_bf16(a0, b0, c0, 0, 0, 0);
      c0 = __builtin_amdgcn_mfma_f32_16x16x32_bf16(a1, b1, c0, 0, 0, 0);
      acc[nt] = c0;
    }
#pragma unroll
    for (int nt = 0; nt < 8; ++nt) {
      float y0 = acc[nt][0], y1 = acc[nt][1], y2 = acc[nt][2], y3 = acc[nt][3];
      ssum[nt] += ((y0 + y1) + (y2 + y3));
      ssq[nt] = fmaf(y0, y0, ssq[nt]);
      ssq[nt] = fmaf(y1, y1, ssq[nt]);
      ssq[nt] = fmaf(y2, y2, ssq[nt]);
      ssq[nt] = fmaf(y3, y3, ssq[nt]);
      float mx = fmaxf(fmaxf(y0, y1), fmaxf(y2, y3));
      float mn = fminf(fminf(y0, y1), fminf(y2, y3));
      mx = fmaxf(mx, __shfl_xor(mx, 16, 64));
      mx = fmaxf(mx, __shfl_xor(mx, 32, 64));
      mn = fminf(mn, __shfl_xor(mn, 16, 64));
      mn = fminf(mn, __shfl_xor(mn, 32, 64));
      if (quad == 0) {
        Mred[w][nt * 16 + l15] = mx;
        Nred[w][nt * 16 + l15] = mn;
      }
    }
    __syncthreads();  // S2: Mred/Nred visible
    {
      int o = t & 127, g = t >> 7;  // waves (0,1)->group0, (2,3)->group1
      float mx = fmaxf(Mred[2 * g][o], Mred[2 * g + 1][o]);
      float mn = fminf(Nred[2 * g][o], Nred[2 * g + 1][o]);
      int bb2 = rowbase >> 15;
      int ss2 = ((rowbase >> 5) & 1023) + g;
      size_t oidx = ((size_t)bb2 * 1024 + ss2) * 128 + o;  // [b][s][o] layout
      gmx[oidx] = mx;
      gmn[oidx] = mn;
    }
    __syncthreads();  // S3: Mred reads done; A reusable next tile
  }
#pragma unroll
  for (int nt = 0; nt < 8; ++nt) {
    float s1 = ssum[nt];
    s1 += __shfl_xor(s1, 16, 64);
    s1 += __shfl_xor(s1, 32, 64);
    float s2 = ssq[nt];
    s2 += __shfl_xor(s2, 16, 64);
    s2 += __shfl_xor(s2, 32, 64);
    if (quad == 0) {
      S1r[w][nt * 16 + l15] = s1;
      S2r[w][nt * 16 + l15] = s2;
    }
  }
  __syncthreads();
  if (t < 128) {
    int o = t;
    float s1 = S1r[0][o] + S1r[1][o] + S1r[2][o] + S1r[3][o];
    float s2 = S2r[0][o] + S2r[1][o] + S2r[2][o] + S2r[3][o];
    partials2[(size_t)o * 1024 + blockIdx.x] = s1;
    partials2[(size_t)(128 + o) * 1024 + blockIdx.x] = s2;
  }
}

// ---------------------------------------------------------------------------
// P4f: feats[b][o][s] = relu(sc2[o] * (sc2>=0 ? gmx : gmn) + sh2[o]).
// [b][s][o] -> [b][o][s] transpose via LDS (pad 130).
// ---------------------------------------------------------------------------
__global__ __launch_bounds__(256) void p4f_kernel(
    const float* __restrict__ gmx, const float* __restrict__ gmn,
    const float* __restrict__ sc2g, const float* __restrict__ sh2g,
    float* __restrict__ feats) {
  __shared__ float MX[16 * 130], MN[16 * 130];
  const int t = threadIdx.x;
  const int bb = blockIdx.x >> 6;
  const int s0 = (blockIdx.x & 63) << 4;
#pragma unroll
  for (int k = 0; k < 8; ++k) {
    int idx = k * 256 + t;
    int s = idx >> 7, o = idx & 127;
    size_t g = ((size_t)bb * 1024 + s0 + s) * 128 + o;
    MX[s * 130 + o] = gmx[g];
    MN[s * 130 + o] = gmn[g];
  }
  __syncthreads();
  const int oo = t >> 1, shf = t & 1;
  const float sc = sc2g[oo], sh = sh2g[oo];
  float* dst = feats + ((size_t)bb * 128 + oo) * 1024 + s0 + shf * 8;
#pragma unroll
  for (int k = 0; k < 8; ++k) {
    int s = shf * 8 + k;
    float v = (sc >= 0.f) ? MX[s * 130 + oo] : MN[s * 130 + oo];
    dst[k] = fmaxf(0.f, fmaf(v, sc, sh));
  }
}

// ---------------------------------------------------------------------------
extern "C" void kernel_launch(void* const* d_in, const int* in_sizes, int n_in,
                              void* d_out, int out_size, void* d_ws, size_t ws_size,
                              hipStream_t stream) {
  const float* xyz = (const float*)d_in[0];
  const float* points = (const float*)d_in[1];
  const float* w0 = (const float*)d_in[2];
  const float* g0 = (const float*)d_in[3];
  const float* b0 = (const float*)d_in[4];
  const float* w1 = (const float*)d_in[5];
  const float* g1 = (const float*)d_in[6];
  const float* b1 = (const float*)d_in[7];
  const float* w2 = (const float*)d_in[8];
  const float* g2 = (const float*)d_in[9];
  const float* b2 = (const float*)d_in[10];

  float* out = (float*)d_out;
  float* newxyz = out;            // (16,1024,3)
  float* feats = out + 49152;     // (16,128,1024)

  char* ws = (char*)d_ws;
  float* P0 = (float*)ws;                                        // 16 MB  [b][n][64]
  // gmx/gmn reuse the P0 region: P0's last consumer is p2; p3 writes these.
  float* gmx = (float*)ws;                                       // 8 MB [b][s][o]
  float* gmn = (float*)(ws + (size_t)(8u << 20));                // 8 MB
  int* gidx = (int*)(ws + (size_t)(16u << 20));                  // 2 MB
  unsigned short* act1 = (unsigned short*)(ws + (size_t)(18u << 20));  // 64 MB bf16
  float* partials0 = (float*)(ws + (size_t)(82u << 20));         // 2 MB   [128][4096]
  float* partials1 = (float*)(ws + (size_t)(84u << 20));         // 0.5 MB [128][1024]
  float* partials2 = (float*)(ws + (size_t)(85u << 20));         // 1 MB   [256][1024]
  float* sc0 = (float*)(ws + (size_t)(86u << 20));               // 6*128 floats
  float* sh0 = sc0 + 128;
  float* sc1 = sc0 + 256;
  float* sh1 = sc0 + 384;
  float* sc2 = sc0 + 512;
  float* sh2 = sc0 + 640;

  fps_kernel<<<16, 256, 0, stream>>>(xyz, newxyz);
  p0_kernel<<<1024, 256, 0, stream>>>(points, w0, P0);
  ballquery_stats0_kernel<<<4096, 256, 0, stream>>>(xyz, newxyz, P0, w0, gidx, partials0);
  finalize_kernel<<<64, 256, 0, stream>>>(partials0, 64, 4096, g0, b0, sc0, sh0);
  p2_kernel<<<1024, 256, 0, stream>>>(xyz, newxyz, P0, gidx, w0, w1, sc0, sh0, act1, partials1);
  finalize_kernel<<<64, 256, 0, stream>>>(partials1, 64, 1024, g1, b1, sc1, sh1);
  p3_kernel<<<1024, 256, 0, stream>>>(act1, w2, sc1, sh1, partials2, gmx, gmn);
  finalize_kernel<<<128, 256, 0, stream>>>(partials2, 128, 1024, g2, b2, sc2, sh2);
  p4f_kernel<<<1024, 256, 0, stream>>>(gmx, gmn, sc2, sh2, feats);
}

// Round 13
// 840.200 us; speedup vs baseline: 1.0731x; 1.0731x over previous
//
#include <hip/hip_runtime.h>

#define DI static __device__ __forceinline__

typedef float v2f __attribute__((ext_vector_type(2)));
typedef __attribute__((ext_vector_type(8))) short bf16x8;
typedef __attribute__((ext_vector_type(4))) float f32x4;

DI unsigned short f2bf(float f) {
  unsigned int u = __float_as_uint(f);
  u = (u + 0x7fffu + ((u >> 16) & 1u)) >> 16;
  return (unsigned short)u;
}
DI float bf2f(unsigned short h) { return __uint_as_float(((unsigned int)h) << 16); }

// DPP wave64 reduce steps (VALU pipe).
#define DPP_MAXU(v, ctrl)                                                      \
  {                                                                            \
    unsigned o_ = (unsigned)__builtin_amdgcn_update_dpp((int)(v), (int)(v),    \
                                                        (ctrl), 0xf, 0xf, false); \
    (v) = (o_ > (v)) ? o_ : (v);                                               \
  }
#define DPP_MINU(v, ctrl)                                                      \
  {                                                                            \
    unsigned o_ = (unsigned)__builtin_amdgcn_update_dpp((int)(v), (int)(v),    \
                                                        (ctrl), 0xf, 0xf, false); \
    (v) = (o_ < (v)) ? o_ : (v);                                               \
  }

// ---------------------------------------------------------------------------
// Fused FPS + P0. Blocks 0..15: FPS, one per batch — EXACT r11 v2f code
// (609 us floor; r10 pk-asm +60, r12 scalar +23 both regressed — frozen).
// FPS waves run at s_setprio(3) so co-resident p0 waves only fill idle
// issue slots (r5's fusion failure was confounded: fps internals changed in
// the same round; this isolates fusion-with-priority).
// Blocks 16..1039: p0 GEMM  P0[b][n][o] = sum_c W0[o][3+c]*points[b][c][n]
// (r12 register-staged W; fmaf order unchanged -> bit-identical P0).
// ---------------------------------------------------------------------------
__global__ __launch_bounds__(256) void fps_p0_kernel(
    const float* __restrict__ xyz, float* __restrict__ newxyz,
    const float* __restrict__ points, const float* __restrict__ w0,
    float* __restrict__ P0) {
  __shared__ union {
    struct {
      float XL[4096 * 3];
      int FI[1024];
      alignas(32) unsigned long long slot[2][4];
    } f;
    float W[64][64];
  } su;
  const int t = threadIdx.x;

  if (blockIdx.x >= 16) {
    // ---------------- p0 GEMM branch (priority 0, fills idle slots) -------
    const int bid = blockIdx.x - 16;
    const int b = bid >> 6;
    const int n0 = (bid & 63) << 6;
    for (int idx = t; idx < 4096; idx += 256) {
      int c = idx >> 6, o = idx & 63;
      su.W[c][o] = w0[o * 67 + 3 + c];
    }
    __syncthreads();
    const int i = t >> 4, j = t & 15;
    const float* Pb = points + (size_t)b * 64 * 4096 + n0 + 4 * i;
    float acc[4][4] = {};
    for (int ch = 0; ch < 4; ++ch) {
      float wr[16][4];
#pragma unroll
      for (int cc = 0; cc < 16; ++cc) {
        float4 wv = *(const float4*)&su.W[ch * 16 + cc][4 * j];
        wr[cc][0] = wv.x; wr[cc][1] = wv.y; wr[cc][2] = wv.z; wr[cc][3] = wv.w;
      }
#pragma unroll
      for (int cc = 0; cc < 16; ++cc) {
        int c = ch * 16 + cc;
        float4 xv = *(const float4*)(Pb + (size_t)c * 4096);
        float xr[4] = {xv.x, xv.y, xv.z, xv.w};
#pragma unroll
        for (int rr = 0; rr < 4; ++rr)
#pragma unroll
          for (int oi = 0; oi < 4; ++oi)
            acc[rr][oi] = fmaf(xr[rr], wr[cc][oi], acc[rr][oi]);
      }
    }
#pragma unroll
    for (int rr = 0; rr < 4; ++rr) {
      float4 vv = make_float4(acc[rr][0], acc[rr][1], acc[rr][2], acc[rr][3]);
      *(float4*)(P0 + ((size_t)b * 4096 + n0 + 4 * i + rr) * 64 + 4 * j) = vv;
    }
    return;
  }

  // ---------------- FPS branch (priority 3) -------------------------------
#if __has_builtin(__builtin_amdgcn_s_setprio)
  __builtin_amdgcn_s_setprio(3);
#endif
  const int b = blockIdx.x;
  const int lane = t & 63, wid = t >> 6;  // 4 waves
  const float* X = xyz + (size_t)b * 4096 * 3;
  for (int idx = t; idx < 12288; idx += 256) su.f.XL[idx] = X[idx];
  v2f px[8], py[8], pz[8], dist[8];
#pragma unroll
  for (int q = 0; q < 8; ++q) {
    int i0 = t + (q << 9);  // t + 512q
    int i1 = i0 + 256;      // t + 512q + 256  (ascending with q)
    px[q] = (v2f){X[i0 * 3 + 0], X[i1 * 3 + 0]};
    py[q] = (v2f){X[i0 * 3 + 1], X[i1 * 3 + 1]};
    pz[q] = (v2f){X[i0 * 3 + 2], X[i1 * 3 + 2]};
    dist[q] = (v2f){3.402823466e38f, 3.402823466e38f};
  }
  __syncthreads();
  float cx = su.f.XL[0], cy = su.f.XL[1], cz = su.f.XL[2];  // farthest = 0
  int fi = 0;
  for (int s = 0; s < 1024; ++s) {
    if (t == 0) su.f.FI[s] = fi;
    float bv = -1.0f;
    unsigned int bi = 0;
    v2f cxv = (v2f){cx, cx}, cyv = (v2f){cy, cy}, czv = (v2f){cz, cz};
#pragma unroll
    for (int q = 0; q < 8; ++q) {
#pragma clang fp contract(off)
      v2f dx = px[q] - cxv;
      v2f dy = py[q] - cyv;
      v2f dz = pz[q] - czv;
      v2f d = (dx * dx + dy * dy) + dz * dz;  // elementwise rn, no contraction
#if __has_builtin(__builtin_elementwise_min)
      v2f nd = __builtin_elementwise_min(dist[q], d);
#else
      v2f nd;
      nd.x = fminf(dist[q].x, d.x);
      nd.y = fminf(dist[q].y, d.y);
#endif
      dist[q] = nd;
      float n0 = nd.x, n1 = nd.y;
      bool c0 = (n0 > bv);
      bv = c0 ? n0 : bv;
      bi = c0 ? (unsigned)(t + (q << 9)) : bi;
      bool c1 = (n1 > bv);
      bv = c1 ? n1 : bv;
      bi = c1 ? (unsigned)(t + (q << 9) + 256) : bi;
    }
    unsigned vb = __float_as_uint(bv);
    unsigned m = vb;
    DPP_MAXU(m, 0x111);
    DPP_MAXU(m, 0x112);
    DPP_MAXU(m, 0x114);
    DPP_MAXU(m, 0x118);
    DPP_MAXU(m, 0x142);
    DPP_MAXU(m, 0x143);
    unsigned wmax = (unsigned)__builtin_amdgcn_readlane((int)m, 63);
    unsigned ik = (vb == wmax) ? bi : 0xFFFFFFFFu;
    DPP_MINU(ik, 0x111);
    DPP_MINU(ik, 0x112);
    DPP_MINU(ik, 0x114);
    DPP_MINU(ik, 0x118);
    DPP_MINU(ik, 0x142);
    DPP_MINU(ik, 0x143);
    unsigned widx = (unsigned)__builtin_amdgcn_readlane((int)ik, 63);
    const int p = s & 1;
    if (lane == 0)
      su.f.slot[p][wid] = ((unsigned long long)wmax << 32) | (unsigned long long)(~widx);
    __syncthreads();
    unsigned long long k0 = su.f.slot[p][0], k1 = su.f.slot[p][1];
    unsigned long long k2 = su.f.slot[p][2], k3 = su.f.slot[p][3];
    unsigned long long m01 = (k0 >= k1) ? k0 : k1;
    unsigned long long m23 = (k2 >= k3) ? k2 : k3;
    unsigned long long win = (m01 >= m23) ? m01 : m23;
    fi = (int)(~(unsigned int)win);  // winner index in [0,4095]
    cx = su.f.XL[fi * 3 + 0];
    cy = su.f.XL[fi * 3 + 1];
    cz = su.f.XL[fi * 3 + 2];
  }
  __syncthreads();
  float* out = newxyz + (size_t)b * 1024 * 3;
  for (int s2 = t; s2 < 1024; s2 += 256) {
    int f = su.f.FI[s2];
    out[s2 * 3 + 0] = su.f.XL[f * 3 + 0];
    out[s2 * 3 + 1] = su.f.XL[f * 3 + 1];
    out[s2 * 3 + 2] = su.f.XL[f * 3 + 2];
  }
}

// ---------------------------------------------------------------------------
// Ball query fused with layer-0 stats (XLA-CPU fp32 emulation VERIFIED r3).
// ---------------------------------------------------------------------------
__global__ __launch_bounds__(256) void ballquery_stats0_kernel(
    const float* __restrict__ xyz, const float* __restrict__ newxyz,
    const float* __restrict__ P0, const float* __restrict__ w0,
    int* __restrict__ gidx, float* __restrict__ partials0) {
  const int t = threadIdx.x;
  const int lane = t & 63, w = t >> 6;
  const int gid = blockIdx.x * 4 + w;  // 0..16383
  const int b = gid >> 10;
  __shared__ int sel[4][32];
  __shared__ float red[4][128];
  const float* Xb = xyz + (size_t)b * 4096 * 3;
  const float cx = newxyz[(size_t)gid * 3 + 0];
  const float cy = newxyz[(size_t)gid * 3 + 1];
  const float cz = newxyz[(size_t)gid * 3 + 2];
  const float cs = __fadd_rn(__fadd_rn(__fmul_rn(cx, cx), __fmul_rn(cy, cy)), __fmul_rn(cz, cz));
  int cnt = 0, first = 0;
  bool found = false;
  for (int base = 0; base < 4096; base += 64) {
    int i = base + lane;
    float x = Xb[i * 3 + 0], y = Xb[i * 3 + 1], z = Xb[i * 3 + 2];
    float xs = __fadd_rn(__fadd_rn(__fmul_rn(x, x), __fmul_rn(y, y)), __fmul_rn(z, z));
    float dot = fmaf(cz, z, fmaf(cy, y, __fmul_rn(cx, x)));  // fma chain, d=0,1,2
    float sqr = __fsub_rn(__fadd_rn(cs, xs), __fmul_rn(2.0f, dot));
    bool ok = sqr <= 0.04f;
    unsigned long long mask = __ballot(ok);
    if (!found && mask != 0ull) { first = base + __builtin_ctzll(mask); found = true; }
    int pre = __popcll(mask & ((1ull << lane) - 1ull));
    int pos = cnt + pre;
    if (ok && pos < 32) sel[w][pos] = i;
    cnt += (int)__popcll(mask);
    if (cnt >= 32) break;
  }
  if (cnt < 32) {
    int pad = found ? first : 0;
    for (int p = cnt + lane; p < 32; p += 64) sel[w][p] = pad;
  }
  __syncthreads();
  if (lane < 32) gidx[(size_t)gid * 32 + lane] = sel[w][lane];
  const int c = lane;
  float wx = w0[c * 67 + 0], wy = w0[c * 67 + 1], wz = w0[c * 67 + 2];
  float ssum = 0.f, ssq = 0.f;
  const float* P0b = P0 + (size_t)b * 4096 * 64;
  for (int k = 0; k < 32; ++k) {
    int g = sel[w][k];
    float gx = Xb[g * 3 + 0] - cx, gy = Xb[g * 3 + 1] - cy, gz = Xb[g * 3 + 2] - cz;
    float a0 = fmaf(wx, gx, fmaf(wy, gy, fmaf(wz, gz, P0b[(size_t)g * 64 + c])));
    ssum += a0;
    ssq = fmaf(a0, a0, ssq);
  }
  red[w][c] = ssum;
  red[w][c + 64] = ssq;
  __syncthreads();
  if (t < 128) {
    float acc = red[0][t] + red[1][t] + red[2][t] + red[3][t];
    partials0[(size_t)t * 4096 + blockIdx.x] = acc;
  }
}

// ---------------------------------------------------------------------------
// finalize BN stats: scale = g*rsqrt(var+eps), shift = b - mean*scale
// ---------------------------------------------------------------------------
__global__ __launch_bounds__(256) void finalize_kernel(
    const float* __restrict__ partials, int C, int nblk,
    const float* __restrict__ gamma, const float* __restrict__ beta,
    float* __restrict__ scale, float* __restrict__ shift) {
  const int c = blockIdx.x, t = threadIdx.x;
  double s1 = 0.0, s2 = 0.0;
  for (int k = t; k < nblk; k += 256) {
    s1 += (double)partials[(size_t)c * nblk + k];
    s2 += (double)partials[(size_t)(C + c) * nblk + k];
  }
  __shared__ double r1[256], r2[256];
  r1[t] = s1;
  r2[t] = s2;
  __syncthreads();
  for (int off = 128; off > 0; off >>= 1) {
    if (t < off) { r1[t] += r1[t + off]; r2[t] += r2[t + off]; }
    __syncthreads();
  }
  if (t == 0) {
    const double M = 524288.0;
    double mean = r1[0] / M;
    double var = r2[0] / M - mean * mean;
    if (var < 0.0) var = 0.0;
    float sc = gamma[c] * (float)(1.0 / sqrt(var + 1e-5));
    scale[c] = sc;
    shift[c] = beta[c] - (float)mean * sc;
  }
}

// ---------------------------------------------------------------------------
// P2 (MFMA): act1_raw = W1 * relu(bn0(act0)); LDS C-staging for coalesced
// act1 stores (VERIFIED r11).
// ---------------------------------------------------------------------------
__global__ __launch_bounds__(256) void p2_kernel(
    const float* __restrict__ xyz, const float* __restrict__ newxyz,
    const float* __restrict__ P0, const int* __restrict__ gidx,
    const float* __restrict__ w0, const float* __restrict__ w1,
    const float* __restrict__ sc0g, const float* __restrict__ sh0g,
    unsigned short* __restrict__ act1, float* __restrict__ partials1) {
  __shared__ unsigned short W1T[64 * 72];  // [o][c] bf16, pad 72
  __shared__ unsigned short A[64 * 72];    // [r][c] bf16, pad 72
  __shared__ unsigned short Cs[64 * 72];   // [r][o] bf16 staging, pad 72
  __shared__ float S1r[4][68], S2r[4][68];
  __shared__ float w0x[64], w0y[64], w0z[64], sc0[64], sh0[64];
  const int t = threadIdx.x;
  const int lane = t & 63, w = t >> 6;
  const int quad = lane >> 4, l15 = lane & 15;
  for (int idx = t; idx < 4096; idx += 256) {
    int o = idx >> 6, c = idx & 63;
    W1T[o * 72 + c] = f2bf(w1[o * 64 + c]);
  }
  if (t < 64) {
    w0x[t] = w0[t * 67 + 0];
    w0y[t] = w0[t * 67 + 1];
    w0z[t] = w0[t * 67 + 2];
    sc0[t] = sc0g[t];
    sh0[t] = sh0g[t];
  }
  __syncthreads();
  const int rl = t >> 2, cq = t & 3;
  float ssum[4] = {}, ssq[4] = {};
  for (int tile = 0; tile < 8; ++tile) {
    const int rowbase = (blockIdx.x * 8 + tile) << 6;
    {
      int r = rowbase + rl;
      int b = r >> 15, s = (r >> 5) & 1023;
      int g = gidx[r];
      const float* Pt = xyz + ((size_t)b * 4096 + g) * 3;
      const float* Ct = newxyz + ((size_t)b * 1024 + s) * 3;
      float dx = Pt[0] - Ct[0], dy = Pt[1] - Ct[1], dz = Pt[2] - Ct[2];
      const float4* p4 = (const float4*)(P0 + ((size_t)b * 4096 + g) * 64 + cq * 16);
      float4 a0 = p4[0], a1 = p4[1], a2 = p4[2], a3 = p4[3];
      float pv[16] = {a0.x, a0.y, a0.z, a0.w, a1.x, a1.y, a1.z, a1.w,
                      a2.x, a2.y, a2.z, a2.w, a3.x, a3.y, a3.z, a3.w};
      unsigned pk[8];
#pragma unroll
      for (int q = 0; q < 8; ++q) {
        int c0 = cq * 16 + 2 * q, c1 = c0 + 1;
        float aa = fmaf(w0x[c0], dx, fmaf(w0y[c0], dy, fmaf(w0z[c0], dz, pv[2 * q])));
        float bb = fmaf(w0x[c1], dx, fmaf(w0y[c1], dy, fmaf(w0z[c1], dz, pv[2 * q + 1])));
        float r0 = fmaxf(0.f, fmaf(aa, sc0[c0], sh0[c0]));
        float r1 = fmaxf(0.f, fmaf(bb, sc0[c1], sh0[c1]));
        pk[q] = (unsigned)f2bf(r0) | ((unsigned)f2bf(r1) << 16);
      }
      uint4* dst = (uint4*)&A[rl * 72 + cq * 16];
      dst[0] = make_uint4(pk[0], pk[1], pk[2], pk[3]);
      dst[1] = make_uint4(pk[4], pk[5], pk[6], pk[7]);
    }
    __syncthreads();  // S1: A visible
    const unsigned short* Arow = &A[(w * 16 + l15) * 72 + quad * 8];
    bf16x8 a0 = *(const bf16x8*)(Arow);
    bf16x8 a1 = *(const bf16x8*)(Arow + 32);
#pragma unroll
    for (int nt = 0; nt < 4; ++nt) {
      const unsigned short* Brow = &W1T[(nt * 16 + l15) * 72 + quad * 8];
      bf16x8 b0 = *(const bf16x8*)(Brow);
      bf16x8 b1 = *(const bf16x8*)(Brow + 32);
      f32x4 c0 = {0.f, 0.f, 0.f, 0.f};
      c0 = __builtin_amdgcn_mfma_f32_16x16x32_bf16(a0, b0, c0, 0, 0, 0);
      c0 = __builtin_amdgcn_mfma_f32_16x16x32_bf16(a1, b1, c0, 0, 0, 0);
      int o = nt * 16 + l15;
      int rloc = w * 16 + quad * 4;
#pragma unroll
      for (int reg = 0; reg < 4; ++reg) {
        float y = c0[reg];
        ssum[nt] += y;
        ssq[nt] = fmaf(y, y, ssq[nt]);
        Cs[(rloc + reg) * 72 + o] = f2bf(y);
      }
    }
    __syncthreads();  // S2: Cs complete (also: all MFMA reads of A done)
    {
      const uint4* src = (const uint4*)&Cs[rl * 72 + cq * 16];
      uint4 v0 = src[0], v1 = src[1];
      uint4* dst = (uint4*)(act1 + ((size_t)rowbase + rl) * 64 + cq * 16);
      dst[0] = v0;
      dst[1] = v1;
    }
  }
#pragma unroll
  for (int nt = 0; nt < 4; ++nt) {
    float s1 = ssum[nt];
    s1 += __shfl_xor(s1, 16, 64);
    s1 += __shfl_xor(s1, 32, 64);
    float s2 = ssq[nt];
    s2 += __shfl_xor(s2, 16, 64);
    s2 += __shfl_xor(s2, 32, 64);
    if (quad == 0) {
      S1r[w][nt * 16 + l15] = s1;
      S2r[w][nt * 16 + l15] = s2;
    }
  }
  __syncthreads();
  if (t < 64) {
    int o = t;
    float s1 = S1r[0][o] + S1r[1][o] + S1r[2][o] + S1r[3][o];
    float s2 = S2r[0][o] + S2r[1][o] + S2r[2][o] + S2r[3][o];
    partials1[(size_t)o * 1024 + blockIdx.x] = s1;
    partials1[(size_t)(64 + o) * 1024 + blockIdx.x] = s2;
  }
}

// ---------------------------------------------------------------------------
// P3 (MFMA): act2_raw = W2 * relu(bn1(act1)) (VERIFIED r9/r11).
// gmx/gmn in [b][s][o] (coalesced).
// ---------------------------------------------------------------------------
__global__ __launch_bounds__(256) void p3_kernel(
    const unsigned short* __restrict__ act1, const float* __restrict__ w2,
    const float* __restrict__ sc1g, const float* __restrict__ sh1g,
    float* __restrict__ partials2, float* __restrict__ gmx,
    float* __restrict__ gmn) {
  __shared__ unsigned short W2T[128 * 72];  // [o][c] bf16, pad 72
  __shared__ unsigned short A[64 * 72];     // [r][k] bf16, pad 72
  __shared__ float Mred[4][132], Nred[4][132];
  __shared__ float S1r[4][132], S2r[4][132];
  __shared__ float sc1[64], sh1[64];
  const int t = threadIdx.x;
  const int lane = t & 63, w = t >> 6;
  const int quad = lane >> 4, l15 = lane & 15;
  for (int idx = t; idx < 8192; idx += 256) {
    int o = idx >> 6, c = idx & 63;
    W2T[o * 72 + c] = f2bf(w2[o * 64 + c]);
  }
  if (t < 64) { sc1[t] = sc1g[t]; sh1[t] = sh1g[t]; }
  __syncthreads();
  const int rl = t >> 2, cq = t & 3;
  float ssum[8] = {}, ssq[8] = {};
  for (int tile = 0; tile < 8; ++tile) {
    const int rowbase = (blockIdx.x * 8 + tile) << 6;
    {
      size_t r = (size_t)rowbase + rl;
      const uint4* pr = (const uint4*)(act1 + r * 64 + cq * 16);
      uint4 aa = pr[0], bb = pr[1];
      unsigned int uu[8] = {aa.x, aa.y, aa.z, aa.w, bb.x, bb.y, bb.z, bb.w};
      unsigned int pk[8];
#pragma unroll
      for (int q = 0; q < 8; ++q) {
        int c = cq * 16 + 2 * q;
        float v0 = bf2f((unsigned short)(uu[q] & 0xffffu));
        float v1 = bf2f((unsigned short)(uu[q] >> 16));
        float r0 = fmaxf(0.f, fmaf(v0, sc1[c], sh1[c]));
        float r1 = fmaxf(0.f, fmaf(v1, sc1[c + 1], sh1[c + 1]));
        pk[q] = (unsigned)f2bf(r0) | ((unsigned)f2bf(r1) << 16);
      }
      uint4* dst = (uint4*)&A[rl * 72 + cq * 16];
      dst[0] = make_uint4(pk[0], pk[1], pk[2], pk[3]);
      dst[1] = make_uint4(pk[4], pk[5], pk[6], pk[7]);
    }
    __syncthreads();  // S1: A visible
    const unsigned short* Arow = &A[(w * 16 + l15) * 72 + quad * 8];
    bf16x8 a0 = *(const bf16x8*)(Arow);
    bf16x8 a1 = *(const bf16x8*)(Arow + 32);
    f32x4 acc[8];
#pragma unroll
    for (int nt = 0; nt < 8; ++nt) {
      const unsigned short* Brow = &W2T[(nt * 16 + l15) * 72 + quad * 8];
      bf16x8 b0 = *(const bf16x8*)(Brow);
      bf16x8 b1 = *(const bf16x8*)(Brow + 32);
      f32x4 c0 = {0.f, 0.f, 0.f, 0.f};
      c0 = __builtin_amdgcn_mfma_f32_16x16x32_bf16(a0, b0, c0, 0, 0, 0);
      c0 = __builtin_amdgcn_mfma_f32_16x16x32_bf16(a1, b1, c0, 0, 0, 0);
      acc[nt] = c0;
    }
#pragma unroll
    for (int nt = 0; nt < 8; ++nt) {
      float y0 = acc[nt][0], y1 = acc[nt][1], y2 = acc[nt][2], y3 = acc[nt][3];
      ssum[nt] += ((y0 + y1) + (y2 + y3));
      ssq[nt] = fmaf(y0, y0, ssq[nt]);
      ssq[nt] = fmaf(y1, y1, ssq[nt]);
      ssq[nt] = fmaf(y2, y2, ssq[nt]);
      ssq[nt] = fmaf(y3, y3, ssq[nt]);
      float mx = fmaxf(fmaxf(y0, y1), fmaxf(y2, y3));
      float mn = fminf(fminf(y0, y1), fminf(y2, y3));
      mx = fmaxf(mx, __shfl_xor(mx, 16, 64));
      mx = fmaxf(mx, __shfl_xor(mx, 32, 64));
      mn = fminf(mn, __shfl_xor(mn, 16, 64));
      mn = fminf(mn, __shfl_xor(mn, 32, 64));
      if (quad == 0) {
        Mred[w][nt * 16 + l15] = mx;
        Nred[w][nt * 16 + l15] = mn;
      }
    }
    __syncthreads();  // S2: Mred/Nred visible
    {
      int o = t & 127, g = t >> 7;  // waves (0,1)->group0, (2,3)->group1
      float mx = fmaxf(Mred[2 * g][o], Mred[2 * g + 1][o]);
      float mn = fminf(Nred[2 * g][o], Nred[2 * g + 1][o]);
      int bb2 = rowbase >> 15;
      int ss2 = ((rowbase >> 5) & 1023) + g;
      size_t oidx = ((size_t)bb2 * 1024 + ss2) * 128 + o;  // [b][s][o] layout
      gmx[oidx] = mx;
      gmn[oidx] = mn;
    }
    __syncthreads();  // S3: Mred reads done; A reusable next tile
  }
#pragma unroll
  for (int nt = 0; nt < 8; ++nt) {
    float s1 = ssum[nt];
    s1 += __shfl_xor(s1, 16, 64);
    s1 += __shfl_xor(s1, 32, 64);
    float s2 = ssq[nt];
    s2 += __shfl_xor(s2, 16, 64);
    s2 += __shfl_xor(s2, 32, 64);
    if (quad == 0) {
      S1r[w][nt * 16 + l15] = s1;
      S2r[w][nt * 16 + l15] = s2;
    }
  }
  __syncthreads();
  if (t < 128) {
    int o = t;
    float s1 = S1r[0][o] + S1r[1][o] + S1r[2][o] + S1r[3][o];
    float s2 = S2r[0][o] + S2r[1][o] + S2r[2][o] + S2r[3][o];
    partials2[(size_t)o * 1024 + blockIdx.x] = s1;
    partials2[(size_t)(128 + o) * 1024 + blockIdx.x] = s2;
  }
}

// ---------------------------------------------------------------------------
// P4f: feats[b][o][s] = relu(sc2[o] * (sc2>=0 ? gmx : gmn) + sh2[o]).
// [b][s][o] -> [b][o][s] transpose via LDS (pad 130).
// ---------------------------------------------------------------------------
__global__ __launch_bounds__(256) void p4f_kernel(
    const float* __restrict__ gmx, const float* __restrict__ gmn,
    const float* __restrict__ sc2g, const float* __restrict__ sh2g,
    float* __restrict__ feats) {
  __shared__ float MX[16 * 130], MN[16 * 130];
  const int t = threadIdx.x;
  const int bb = blockIdx.x >> 6;
  const int s0 = (blockIdx.x & 63) << 4;
#pragma unroll
  for (int k = 0; k < 8; ++k) {
    int idx = k * 256 + t;
    int s = idx >> 7, o = idx & 127;
    size_t g = ((size_t)bb * 1024 + s0 + s) * 128 + o;
    MX[s * 130 + o] = gmx[g];
    MN[s * 130 + o] = gmn[g];
  }
  __syncthreads();
  const int oo = t >> 1, shf = t & 1;
  const float sc = sc2g[oo], sh = sh2g[oo];
  float* dst = feats + ((size_t)bb * 128 + oo) * 1024 + s0 + shf * 8;
#pragma unroll
  for (int k = 0; k < 8; ++k) {
    int s = shf * 8 + k;
    float v = (sc >= 0.f) ? MX[s * 130 + oo] : MN[s * 130 + oo];
    dst[k] = fmaxf(0.f, fmaf(v, sc, sh));
  }
}

// ---------------------------------------------------------------------------
extern "C" void kernel_launch(void* const* d_in, const int* in_sizes, int n_in,
                              void* d_out, int out_size, void* d_ws, size_t ws_size,
                              hipStream_t stream) {
  const float* xyz = (const float*)d_in[0];
  const float* points = (const float*)d_in[1];
  const float* w0 = (const float*)d_in[2];
  const float* g0 = (const float*)d_in[3];
  const float* b0 = (const float*)d_in[4];
  const float* w1 = (const float*)d_in[5];
  const float* g1 = (const float*)d_in[6];
  const float* b1 = (const float*)d_in[7];
  const float* w2 = (const float*)d_in[8];
  const float* g2 = (const float*)d_in[9];
  const float* b2 = (const float*)d_in[10];

  float* out = (float*)d_out;
  float* newxyz = out;            // (16,1024,3)
  float* feats = out + 49152;     // (16,128,1024)

  char* ws = (char*)d_ws;
  float* P0 = (float*)ws;                                        // 16 MB  [b][n][64]
  // gmx/gmn reuse the P0 region: P0's last consumer is p2; p3 writes these.
  float* gmx = (float*)ws;                                       // 8 MB [b][s][o]
  float* gmn = (float*)(ws + (size_t)(8u << 20));                // 8 MB
  int* gidx = (int*)(ws + (size_t)(16u << 20));                  // 2 MB
  unsigned short* act1 = (unsigned short*)(ws + (size_t)(18u << 20));  // 64 MB bf16
  float* partials0 = (float*)(ws + (size_t)(82u << 20));         // 2 MB   [128][4096]
  float* partials1 = (float*)(ws + (size_t)(84u << 20));         // 0.5 MB [128][1024]
  float* partials2 = (float*)(ws + (size_t)(85u << 20));         // 1 MB   [256][1024]
  float* sc0 = (float*)(ws + (size_t)(86u << 20));               // 6*128 floats
  float* sh0 = sc0 + 128;
  float* sc1 = sc0 + 256;
  float* sh1 = sc0 + 384;
  float* sc2 = sc0 + 512;
  float* sh2 = sc0 + 640;

  fps_p0_kernel<<<1040, 256, 0, stream>>>(xyz, newxyz, points, w0, P0);
  ballquery_stats0_kernel<<<4096, 256, 0, stream>>>(xyz, newxyz, P0, w0, gidx, partials0);
  finalize_kernel<<<64, 256, 0, stream>>>(partials0, 64, 4096, g0, b0, sc0, sh0);
  p2_kernel<<<1024, 256, 0, stream>>>(xyz, newxyz, P0, gidx, w0, w1, sc0, sh0, act1, partials1);
  finalize_kernel<<<64, 256, 0, stream>>>(partials1, 64, 1024, g1, b1, sc1, sh1);
  p3_kernel<<<1024, 256, 0, stream>>>(act1, w2, sc1, sh1, partials2, gmx, gmn);
  finalize_kernel<<<128, 256, 0, stream>>>(partials2, 128, 1024, g2, b2, sc2, sh2);
  p4f_kernel<<<1024, 256, 0, stream>>>(gmx, gmn, sc2, sh2, feats);
}